// Round 8
// baseline (323.739 us; speedup 1.0000x reference)
//
#include <hip/hip_runtime.h>
#include <hip/hip_bf16.h>

// KroneckerMixer: B=64, N=1024, K=64, BASIS=8, T=0.2, 20 sinkhorn iters.
// R14 pipeline (bf16 path, ws >= 40.25 MB):
//   k_front : fused, grid 288 x 256, __launch_bounds__(256, 2). (R13 geometry:
//     256-thread blocks keep every register array resident; VGPR=128, no
//     scratch — verified by R13 counters.)
//     Blocks 0..31  = A-sinkhorn u/v solver: 32 rows/block, thread holds
//       e[8][16] (lane-stride-64 cols). Per iter: 8 DPP row reduces -> u;
//       col partials -> 4-wave LDS reduce -> per-block partial store (sc1).
//       *** R14 exchange fix: detection via ONE arrival counter per
//       iteration. Producer: stores -> __syncthreads (vmcnt(0) drain =
//       global visibility, same contract as R9-R13) -> thread0 fetch_add.
//       Consumer: thread0 alone polls the single counter word with s_sleep
//       backoff until ==32, then the block gathers ONCE (coalesced, no
//       spinning). Value-as-flag retry kept as a safety net only. This
//       removes the R13 polling storm (8192 threads x 128 sc1 loads in
//       tight loops) that congested the fabric at ~8.3 us/iter. ***
//     Blocks 32..287 = W-path (R11/R13 verified, byte-identical): one n per
//       WAVE, fully in-register; 63-op ds_bpermute butterfly row sums; u via
//       per-wave 256B LDS line; col pass lane-local; in-wave matmul.
//   k_xt    : transpose + v-scale + hi/lo split XL -> XTh/XTl bf16 [c][n].
//   k_gemm3 : out[m][c] = u_m*(Eh*XTh + El*XTh + Eh*XTl) via mfma 16x16x32.
// Fallback (small ws): fp32 k_gemm reading E0 with u/v folded.

#define N_DIM 1024
#define INV_T 5.0f
#define ABLK 32  // A-sinkhorn blocks (32 rows each)

typedef __attribute__((ext_vector_type(8))) short short8;
typedef __attribute__((ext_vector_type(4))) float float4v;

// ---------------- wave64 sum reduction via DPP (VALU pipe) -------------------
// Result valid in lane 63.
__device__ __forceinline__ float wave_red_sum(float x) {
#define DPP_ADD(C)                                                            \
  {                                                                           \
    int _y = __builtin_amdgcn_update_dpp(0, __float_as_int(x), (C), 0xf, 0xf, \
                                         true);                               \
    x += __int_as_float(_y);                                                  \
  }
  DPP_ADD(0x111);
  DPP_ADD(0x112);
  DPP_ADD(0x114);
  DPP_ADD(0x118);
  DPP_ADD(0x142);
  DPP_ADD(0x143);
#undef DPP_ADD
  return x;
}

// ---------------- kernel 1: fused sinkA(u,v) + wpath -------------------------
// grid 288 x 256.
__global__ __launch_bounds__(256, 2) void k_front(
    const float* __restrict__ x, const float* __restrict__ L,
    const float* __restrict__ W1, const float* __restrict__ WV,
    float* __restrict__ E0, __hip_bfloat16* __restrict__ Eh,
    __hip_bfloat16* __restrict__ El, float* __restrict__ P,
    unsigned* __restrict__ ctrl, float* __restrict__ u_g,
    float* __restrict__ v_g, float* __restrict__ XL, int write_bf16) {
  __shared__ __align__(16) float smem[5136];
  const int t = threadIdx.x;  // 0..255
  const int bid = blockIdx.x;
  const int lane = t & 63;
  const int w = t >> 6;  // 0..3

  if (bid < ABLK) {
    // =================== A-sinkhorn u/v role (E in registers) ===============
    // Thread layout: e[j][k] = E[r0 + 8w + j][k*64 + lane], j<8, k<16.
    float* v_s = smem;          // [1024]
    float* red = smem + 1024;   // [4][1028] cross-wave col reduce
    const int b = bid;
    const int r0 = b * 32;
    unsigned* cnt = ctrl;  // [20] per-iteration arrival counters (zeroed)

    // ---- prologue: e = exp(L/T); emit Eh/El (bf16 hi/lo) or E0 (fp32)
    float e[8][16];
#pragma unroll
    for (int j = 0; j < 8; ++j) {
      const int r = r0 + 8 * w + j;
      const float* Lr = L + (size_t)r * N_DIM + lane;
#pragma unroll
      for (int k = 0; k < 16; ++k) e[j][k] = __expf(Lr[k * 64] * INV_T);
      if (write_bf16) {
        __hip_bfloat16* EhR = Eh + (size_t)r * N_DIM + lane;
        __hip_bfloat16* ElR = El + (size_t)r * N_DIM + lane;
#pragma unroll
        for (int k = 0; k < 16; ++k) {
          __hip_bfloat16 h = __float2bfloat16(e[j][k]);
          EhR[k * 64] = h;
          ElR[k * 64] = __float2bfloat16(e[j][k] - __bfloat162float(h));
        }
      } else {
        float* ER = E0 + (size_t)r * N_DIM + lane;
#pragma unroll
        for (int k = 0; k < 16; ++k) ER[k * 64] = e[j][k];
      }
    }
    // v == 1 for iter 0
    v_s[t] = 1.0f;
    v_s[t + 256] = 1.0f;
    v_s[t + 512] = 1.0f;
    v_s[t + 768] = 1.0f;
    __syncthreads();

    for (int it = 0; it < 20; ++it) {
      // ---- row pass: u_i = 1/sum_c e[i][c]*v[c]
      float vv[16];
#pragma unroll
      for (int k = 0; k < 16; ++k) vv[k] = v_s[k * 64 + lane];
      float u[8];
#pragma unroll
      for (int j = 0; j < 8; ++j) {
        float p = 0.f;
#pragma unroll
        for (int k = 0; k < 16; ++k) p += e[j][k] * vv[k];
        p = wave_red_sum(p);  // lane 63
        u[j] = 1.0f /
               __int_as_float(__builtin_amdgcn_readlane(__float_as_int(p), 63));
      }
      // ---- col partials for this wave's 8 rows (col = k*64+lane)
#pragma unroll
      for (int k = 0; k < 16; ++k) {
        float cpl = e[0][k] * u[0] + e[1][k] * u[1] + e[2][k] * u[2] +
                    e[3][k] * u[3] + e[4][k] * u[4] + e[5][k] * u[5] +
                    e[6][k] * u[6] + e[7][k] * u[7];
        red[w * 1028 + k * 64 + lane] = cpl;
      }
      if (it == 19 && lane == 0) {
#pragma unroll
        for (int j = 0; j < 8; ++j) u_g[r0 + 8 * w + j] = u[j];
      }
      __syncthreads();
      // ---- block col sums (thread t -> cols t, t+256, t+512, t+768) + post
      float* Pit = P + (size_t)it * (ABLK * N_DIM);
#pragma unroll
      for (int cc = 0; cc < 4; ++cc) {
        const int c = t + cc * 256;
        float cp =
            red[c] + red[1028 + c] + red[2 * 1028 + c] + red[3 * 1028 + c];
        __hip_atomic_store(&Pit[b * N_DIM + c], cp, __ATOMIC_RELAXED,
                           __HIP_MEMORY_SCOPE_AGENT);
      }
      // ---- drain: vmcnt(0) at barrier => partials globally visible
      __syncthreads();
      // ---- signal + single-poller detection (one word, s_sleep backoff)
      if (t == 0) {
        unsigned prev = __hip_atomic_fetch_add(&cnt[it], 1u, __ATOMIC_RELAXED,
                                               __HIP_MEMORY_SCOPE_AGENT);
        if (prev != (unsigned)(ABLK - 1)) {
          while (__hip_atomic_load(&cnt[it], __ATOMIC_RELAXED,
                                   __HIP_MEMORY_SCOPE_AGENT) < (unsigned)ABLK)
            __builtin_amdgcn_s_sleep(2);
        }
      }
      __syncthreads();
      // ---- gather once (all partials present); zero-retry kept as safety
      for (int cc = 0; cc < 4; ++cc) {
        const int c = t + cc * 256;
        unsigned vals[ABLK];
#pragma unroll
        for (int pb = 0; pb < ABLK; ++pb)
          vals[pb] =
              __hip_atomic_load((const unsigned*)&Pit[pb * N_DIM + c],
                                __ATOMIC_RELAXED, __HIP_MEMORY_SCOPE_AGENT);
        for (;;) {
          unsigned miss = 0u;
#pragma unroll
          for (int pb = 0; pb < ABLK; ++pb) miss |= (vals[pb] == 0u) ? 1u : 0u;
          if (miss == 0u) break;
          __builtin_amdgcn_s_sleep(1);
#pragma unroll
          for (int pb = 0; pb < ABLK; ++pb)
            if (vals[pb] == 0u)
              vals[pb] = __hip_atomic_load(
                  (const unsigned*)&Pit[pb * N_DIM + c], __ATOMIC_RELAXED,
                  __HIP_MEMORY_SCOPE_AGENT);
        }
        float s2 = 0.f;
#pragma unroll
        for (int pb = 0; pb < ABLK; ++pb) s2 += __uint_as_float(vals[pb]);
        v_s[c] = 1.0f / s2;
      }
      __syncthreads();
    }
    // ---- epilogue: v from block 0 (u already written at it==19)
    if (b == 0) {
#pragma unroll
      for (int cc = 0; cc < 4; ++cc) v_g[t + cc * 256] = v_s[t + cc * 256];
    }
    return;
  }

  // =========== W-path: one n per wave, fully in-register ====================
  float* ug = smem + w * 64;  // per-wave 256B u-broadcast line
  const int n = (bid - ABLK) * 4 + w;  // 0..1023 exactly

  const int pidx = lane << 2;  // bpermute byte index base

  // ---- logits: lane c holds E[:,c]; e[i] = exp(INV_T * sum_k w1 WV[k][i][c])
  float w1[8];
#pragma unroll
  for (int k = 0; k < 8; ++k) w1[k] = W1[n * 8 + k];
  float e[64];
#pragma unroll
  for (int i = 0; i < 64; ++i) {
    float acc = 0.f;
#pragma unroll
    for (int k = 0; k < 8; ++k) acc += w1[k] * WV[k * 4096 + i * 64 + lane];
    e[i] = __expf(acc * INV_T);
  }

  // ---- 20 sinkhorn iterations, in-wave
  float v = 1.0f;
  for (int it = 0; it < 20; ++it) {
    // row sums via register butterfly reduce-transpose:
    // lane l ends with rowsum[l] = sum_c e_c[l]*v_c
    float a[32];
    {
      const bool hi = (lane & 32) != 0;
      const int pj = pidx ^ (32 << 2);
#pragma unroll
      for (int j = 0; j < 32; ++j) {
        float s0 = (hi ? e[j] : e[j + 32]) * v;
        float k0 = (hi ? e[j + 32] : e[j]) * v;
        a[j] = k0 + __int_as_float(__builtin_amdgcn_ds_bpermute(
                        pj, __float_as_int(s0)));
      }
    }
#define BSTAGE(D)                                                          \
  {                                                                        \
    const bool hi = (lane & (D)) != 0;                                     \
    const int pj = pidx ^ ((D) << 2);                                      \
    _Pragma("unroll") for (int j = 0; j < (D); ++j) {                      \
      float s0 = hi ? a[j] : a[j + (D)];                                   \
      float k0 = hi ? a[j + (D)] : a[j];                                   \
      a[j] = k0 + __int_as_float(                                          \
                      __builtin_amdgcn_ds_bpermute(pj, __float_as_int(s0))); \
    }                                                                      \
  }
    BSTAGE(16)
    BSTAGE(8)
    BSTAGE(4)
    BSTAGE(2)
    BSTAGE(1)
#undef BSTAGE
    const float u_l = 1.0f / a[0];
    ug[lane] = u_l;  // same-wave in-order DS pipe: reads below see this
    // col pass: v_c = 1/sum_i e[i][c]*u[i]  (u broadcast, v lane-local)
    float s2 = 0.f;
#pragma unroll
    for (int q = 0; q < 16; ++q) {
      float4 u4 = *(const float4*)&ug[4 * q];
      s2 += e[4 * q] * u4.x + e[4 * q + 1] * u4.y + e[4 * q + 2] * u4.z +
            e[4 * q + 3] * u4.w;
    }
    v = 1.0f / s2;
  }

  // ---- fold u into e:  e[i] <- e[i]*u[i]   (W[i][c] = e[i]*u[i]*v)
#pragma unroll
  for (int q = 0; q < 16; ++q) {
    float4 u4 = *(const float4*)&ug[4 * q];
    e[4 * q] *= u4.x;
    e[4 * q + 1] *= u4.y;
    e[4 * q + 2] *= u4.z;
    e[4 * q + 3] *= u4.w;
  }

  // ---- in-wave matmul: x_local[bb][c] = v * sum_i x[bb][n*64+i]*e[i]
  const float* xn = x + (size_t)n * 64;
  float* xl = XL + (size_t)n * 4096;
#pragma unroll 4
  for (int bb = 0; bb < 64; ++bb) {
    const float* xr = xn + (size_t)bb * 65536;
    float acc = 0.f;
#pragma unroll
    for (int q = 0; q < 16; ++q) {
      float4 xb = *(const float4*)&xr[4 * q];  // lane-uniform -> broadcast
      acc += xb.x * e[4 * q] + xb.y * e[4 * q + 1] + xb.z * e[4 * q + 2] +
             xb.w * e[4 * q + 3];
    }
    xl[bb * 64 + lane] = acc * v;  // coalesced 256B store
  }
}

// ---------------- kernel 2b: transpose + v-scale + hi/lo split ---------------
// XTh/XTl[c][n] = hi/lo bf16 of (v[n] * XL[n][c]).
__global__ __launch_bounds__(256) void k_xt(const float* __restrict__ XL,
                                            const float* __restrict__ v_g,
                                            __hip_bfloat16* __restrict__ XTh,
                                            __hip_bfloat16* __restrict__ XTl) {
  __shared__ float T[64 * 68];
  __shared__ float vsh[64];
  const int t = threadIdx.x;
  const int n0 = blockIdx.x * 64;
  const int c0 = blockIdx.y * 64;
  if (t < 64) vsh[t] = v_g[n0 + t];
  {
    const int r = t >> 4;         // 0..15
    const int c4 = (t & 15) * 4;  // 0..60
#pragma unroll
    for (int p = 0; p < 4; ++p) {
      float4 f =
          *(const float4*)&XL[(size_t)(n0 + r + 16 * p) * 4096 + c0 + c4];
      *(float4*)&T[(r + 16 * p) * 68 + c4] = f;
    }
  }
  __syncthreads();
  const int cl = t >> 2;        // 0..63
  const int nb = (t & 3) * 16;  // 0,16,32,48
  __align__(16) __hip_bfloat16 hbuf[16];
  __align__(16) __hip_bfloat16 lbuf[16];
#pragma unroll
  for (int j = 0; j < 16; ++j) {
    float xv = T[(nb + j) * 68 + cl] * vsh[nb + j];
    __hip_bfloat16 h = __float2bfloat16(xv);
    hbuf[j] = h;
    lbuf[j] = __float2bfloat16(xv - __bfloat162float(h));
  }
  const size_t off = (size_t)(c0 + cl) * 1024 + n0 + nb;
  *(uint4*)&XTh[off] = *(uint4*)&hbuf[0];
  *(uint4*)&XTh[off + 8] = *(uint4*)&hbuf[8];
  *(uint4*)&XTl[off] = *(uint4*)&lbuf[0];
  *(uint4*)&XTl[off + 8] = *(uint4*)&lbuf[8];
}

// ---------------- kernel 3 (bf16): out = u ⊙ (Eh*XTh + El*XTh + Eh*XTl) ------
// D[m=1024][c=4096], 128x128 block tile, 4 waves each 64x64 of 16x16x32 MFMA.
#define LSTR 72  // padded LDS row stride (elements)
__global__ __launch_bounds__(256) void k_gemm3(
    const ushort* __restrict__ Eh, const ushort* __restrict__ El,
    const ushort* __restrict__ XTh, const ushort* __restrict__ XTl,
    const float* __restrict__ u_g, float* __restrict__ out) {
  __shared__ ushort As[128 * LSTR];
  __shared__ ushort Xs[128 * LSTR];
  __shared__ float ush[128];
  const int t = threadIdx.x;
  const int m0 = blockIdx.x * 128;
  const int c0 = blockIdx.y * 128;
  const int wid = t >> 6, lane = t & 63;
  const int wm = (wid & 1) * 64, wc = (wid >> 1) * 64;
  const int lm = lane & 15, q = lane >> 4;
  const int sr = t >> 1;        // staging row 0..127
  const int sc = (t & 1) * 32;  // staging k-offset: [sc, sc+32)
  if (t < 128) ush[t] = u_g[m0 + t];

  float4v acc[4][4];
#pragma unroll
  for (int i = 0; i < 4; ++i)
#pragma unroll
    for (int j = 0; j < 4; ++j) acc[i][j] = (float4v){0.f, 0.f, 0.f, 0.f};

  for (int seg = 0; seg < 3; ++seg) {
    const ushort* Ag = (seg == 1) ? El : Eh;
    const ushort* Xg = (seg == 2) ? XTl : XTh;
    for (int k0 = 0; k0 < 1024; k0 += 64) {
      __syncthreads();
      const ushort* ag = Ag + (size_t)(m0 + sr) * 1024 + k0 + sc;
      const ushort* xg = Xg + (size_t)(c0 + sr) * 1024 + k0 + sc;
      uint4 a0 = *(const uint4*)(ag);
      uint4 a1 = *(const uint4*)(ag + 8);
      uint4 a2 = *(const uint4*)(ag + 16);
      uint4 a3 = *(const uint4*)(ag + 24);
      uint4 x0 = *(const uint4*)(xg);
      uint4 x1 = *(const uint4*)(xg + 8);
      uint4 x2 = *(const uint4*)(xg + 16);
      uint4 x3 = *(const uint4*)(xg + 24);
      *(uint4*)&As[sr * LSTR + sc] = a0;
      *(uint4*)&As[sr * LSTR + sc + 8] = a1;
      *(uint4*)&As[sr * LSTR + sc + 16] = a2;
      *(uint4*)&As[sr * LSTR + sc + 24] = a3;
      *(uint4*)&Xs[sr * LSTR + sc] = x0;
      *(uint4*)&Xs[sr * LSTR + sc + 8] = x1;
      *(uint4*)&Xs[sr * LSTR + sc + 16] = x2;
      *(uint4*)&Xs[sr * LSTR + sc + 24] = x3;
      __syncthreads();
#pragma unroll
      for (int kk = 0; kk < 2; ++kk) {
        short8 af[4], xf[4];
#pragma unroll
        for (int i = 0; i < 4; ++i)
          af[i] = *(const short8*)&As[(wm + 16 * i + lm) * LSTR + kk * 32 +
                                      q * 8];
#pragma unroll
        for (int j = 0; j < 4; ++j)
          xf[j] = *(const short8*)&Xs[(wc + 16 * j + lm) * LSTR + kk * 32 +
                                      q * 8];
#pragma unroll
        for (int i = 0; i < 4; ++i)
#pragma unroll
          for (int j = 0; j < 4; ++j)
            acc[i][j] = __builtin_amdgcn_mfma_f32_16x16x32_bf16(
                af[i], xf[j], acc[i][j], 0, 0, 0);
      }
    }
  }
  // epilogue: D row = q*4 + reg, col = lm (m89-verified); scale by u_m
#pragma unroll
  for (int i = 0; i < 4; ++i) {
#pragma unroll
    for (int j = 0; j < 4; ++j) {
      const int ml = wm + 16 * i + q * 4;
      const int m = m0 + ml;
      const int c = c0 + wc + 16 * j + lm;
      const int bb = c >> 6, o = c & 63;
      float* dst = out + (size_t)bb * 65536 + (size_t)m * 64 + o;
#pragma unroll
      for (int r = 0; r < 4; ++r) dst[64 * r] = acc[i][j][r] * ush[ml + r];
    }
  }
}

// ---------------- kernel 3 (fp32 fallback): out = u ⊙ (E0·(v⊙XL)) ------------
__global__ __launch_bounds__(256) void k_gemm(const float* __restrict__ E0,
                                              const float* __restrict__ XL,
                                              const float* __restrict__ u_g,
                                              const float* __restrict__ v_g,
                                              float* __restrict__ out) {
  __shared__ float Asm[32][132];
  __shared__ float Xsm[32][132];
  const int t = threadIdx.x;
  const int m0 = blockIdx.x * 128;
  const int c0 = blockIdx.y * 128;
  const int my8 = (t >> 4) * 8;
  const int cx8 = (t & 15) * 8;
  const int kk = t & 31;
  const int rr = t >> 5;
  float acc[8][8] = {};

  for (int k0 = 0; k0 < 1024; k0 += 32) {
#pragma unroll
    for (int s = 0; s < 16; ++s)
      Asm[kk][rr + 8 * s] = E0[(size_t)(m0 + rr + 8 * s) * 1024 + k0 + kk];
#pragma unroll
    for (int s = 0; s < 4; ++s) {
      const int krow = k0 + rr + 8 * s;
      float vk = v_g[krow];
      float4 f = *(const float4*)&XL[(size_t)krow * 4096 + c0 + kk * 4];
      f.x *= vk;
      f.y *= vk;
      f.z *= vk;
      f.w *= vk;
      *(float4*)&Xsm[rr + 8 * s][kk * 4] = f;
    }
    __syncthreads();
#pragma unroll
    for (int k = 0; k < 32; ++k) {
      float a[8], xv[8];
      *(float4*)&a[0] = *(const float4*)&Asm[k][my8];
      *(float4*)&a[4] = *(const float4*)&Asm[k][my8 + 4];
      *(float4*)&xv[0] = *(const float4*)&Xsm[k][cx8];
      *(float4*)&xv[4] = *(const float4*)&Xsm[k][cx8 + 4];
#pragma unroll
      for (int i = 0; i < 8; ++i)
#pragma unroll
        for (int j = 0; j < 8; ++j) acc[i][j] += a[i] * xv[j];
    }
    __syncthreads();
  }

#pragma unroll
  for (int i = 0; i < 8; ++i) {
    const int m = m0 + my8 + i;
    const float um = u_g[m];
    const int c = c0 + cx8;
    const int bb = c >> 6, o = c & 63;
    float* dst = out + (size_t)bb * 65536 + (size_t)m * 64 + o;
#pragma unroll
    for (int j = 0; j < 8; ++j) dst[j] = acc[i][j] * um;
  }
}

// ---------------- launcher ---------------------------------------------------
extern "C" void kernel_launch(void* const* d_in, const int* in_sizes, int n_in,
                              void* d_out, int out_size, void* d_ws,
                              size_t ws_size, hipStream_t stream) {
  (void)in_sizes;
  (void)n_in;
  (void)out_size;
  const float* x = (const float*)d_in[0];
  const float* Alog = (const float*)d_in[1];
  const float* W1 = (const float*)d_in[2];
  const float* WV = (const float*)d_in[3];
  float* out = (float*)d_out;

  char* ws = (char*)d_ws;
  const size_t MB = 1024 * 1024;
  const size_t KB = 1024;
  const bool use_bf16 = ws_size >= (40 * MB + 256 * KB);
  const size_t P_BYTES = 20ull * ABLK * N_DIM * sizeof(float);  // 2.5 MB

  float* E0;
  float* XL;
  float* P;
  float* u_g;
  float* v_g;
  unsigned* ctrl;
  __hip_bfloat16 *Eh = nullptr, *El = nullptr, *XTh = nullptr, *XTl = nullptr;
  if (use_bf16) {
    P = (float*)(ws);                       // 2.5 MB (in dead E0 slot, 4 MB)
    E0 = (float*)(ws);                      // unused when write_bf16=1
    XL = (float*)(ws + 4 * MB);             // 16 MB
    Eh = (__hip_bfloat16*)(ws + 20 * MB);   // 2 MB
    El = (__hip_bfloat16*)(ws + 22 * MB);   // 2 MB
    XTh = (__hip_bfloat16*)(ws + 24 * MB);  // 8 MB
    XTl = (__hip_bfloat16*)(ws + 32 * MB);  // 8 MB -> 40 MB
    u_g = (float*)(ws + 40 * MB);                 // 4 KB
    v_g = (float*)(ws + 40 * MB + 4 * KB);        // 4 KB
    ctrl = (unsigned*)(ws + 40 * MB + 8 * KB);    // 4 KB (arrival counters)
  } else {
    E0 = (float*)(ws);                      // 4 MB
    XL = (float*)(ws + 4 * MB);             // 16 MB
    P = (float*)(ws + 20 * MB);             // 2.5 MB
    u_g = (float*)(ws + 20 * MB + 2560 * KB);
    v_g = (float*)(ws + 20 * MB + 2564 * KB);
    ctrl = (unsigned*)(ws + 20 * MB + 2568 * KB);
  }

  hipMemsetAsync(ctrl, 0, 4096, stream);
  hipMemsetAsync(P, 0, P_BYTES, stream);
  hipLaunchKernelGGL(k_front, dim3(ABLK + 256), dim3(256), 0, stream, x, Alog,
                     W1, WV, E0, Eh, El, P, ctrl, u_g, v_g, XL,
                     use_bf16 ? 1 : 0);
  if (use_bf16) {
    hipLaunchKernelGGL(k_xt, dim3(16, 64), dim3(256), 0, stream, XL, v_g, XTh,
                       XTl);
    hipLaunchKernelGGL(k_gemm3, dim3(8, 32), dim3(256), 0, stream,
                       (const ushort*)Eh, (const ushort*)El, (const ushort*)XTh,
                       (const ushort*)XTl, u_g, out);
  } else {
    hipLaunchKernelGGL(k_gemm, dim3(8, 32), dim3(256), 0, stream, E0, XL, u_g,
                       v_g, out);
  }
}

// Round 9
// 317.522 us; speedup vs baseline: 1.0196x; 1.0196x over previous
//
#include <hip/hip_runtime.h>
#include <hip/hip_bf16.h>

// KroneckerMixer: B=64, N=1024, K=64, BASIS=8, T=0.2, 20 sinkhorn iters.
// R15 pipeline (bf16 path, ws >= 40.25 MB):
//   k_front : fused, grid 288 x 256, __launch_bounds__(256, 2). (R13 geometry,
//     VGPR cap 256 under either launch_bounds interpretation; R13-verified
//     no-spill: VGPR=128, WRITE_SIZE ~= real data.)
//     Blocks 0..31  = A-sinkhorn (R13-exact exchange: per-iteration buffers,
//       value-as-flag spin gather — best measured variant, ~8us/iter).
//       NEW: epilogue writes Mh/Ml = hi/lo bf16 of (u_m * E[m,k] * v_k) —
//       u,v folded INTO the GEMM A-operand in fp32 before the split, so
//       k_gemm3 needs no u-scale and k_xt no v-scale. Same error budget.
//     Blocks 32..287 = W-path (R11/R13 verified, byte-identical).
//   k_xt    : pure transpose + hi/lo split XL -> XTh/XTl bf16 [c][n].
//   k_gemm3 : REBUILT. out[m][c] = Mh*XTh + Ml*XTh + Mh*XTl via mfma
//     16x16x32 bf16, 128x128 tile, 4 waves. Double-buffered LDS (4x16KB),
//     global_load_lds width-16 staging (8 calls/tile), prefetch next K-tile
//     BEFORE the MFMA phase, ONE barrier per K-step: load latency hides
//     under MFMA even at 1 block/CU. 48 flattened K-steps (3 segs x 16).
// Fallback (small ws): fp32 k_gemm reading E0 with u/v folded.

#define N_DIM 1024
#define INV_T 5.0f
#define ABLK 32  // A-sinkhorn blocks (32 rows each)

typedef __attribute__((ext_vector_type(8))) short short8;
typedef __attribute__((ext_vector_type(4))) float float4v;

// ---------------- wave64 sum reduction via DPP (VALU pipe) -------------------
// Result valid in lane 63.
__device__ __forceinline__ float wave_red_sum(float x) {
#define DPP_ADD(C)                                                            \
  {                                                                           \
    int _y = __builtin_amdgcn_update_dpp(0, __float_as_int(x), (C), 0xf, 0xf, \
                                         true);                               \
    x += __int_as_float(_y);                                                  \
  }
  DPP_ADD(0x111);
  DPP_ADD(0x112);
  DPP_ADD(0x114);
  DPP_ADD(0x118);
  DPP_ADD(0x142);
  DPP_ADD(0x143);
#undef DPP_ADD
  return x;
}

// ---------------- async global->LDS, 16B per lane ----------------------------
// LDS dest is wave-uniform base + lane*16 (HW); global src is per-lane.
__device__ __forceinline__ void stage16(const ushort* g, ushort* l) {
  __builtin_amdgcn_global_load_lds(
      (const __attribute__((address_space(1))) void*)g,
      (__attribute__((address_space(3))) void*)l, 16, 0, 0);
}

// ---------------- kernel 1: fused sinkA(u,v)+M-emit + wpath ------------------
// grid 288 x 256.
__global__ __launch_bounds__(256, 2) void k_front(
    const float* __restrict__ x, const float* __restrict__ L,
    const float* __restrict__ W1, const float* __restrict__ WV,
    float* __restrict__ E0, __hip_bfloat16* __restrict__ Mh,
    __hip_bfloat16* __restrict__ Ml, float* __restrict__ P,
    unsigned* __restrict__ ctrl, float* __restrict__ u_g,
    float* __restrict__ v_g, float* __restrict__ XL, int write_bf16) {
  __shared__ __align__(16) float smem[5136];
  const int t = threadIdx.x;  // 0..255
  const int bid = blockIdx.x;
  const int lane = t & 63;
  const int w = t >> 6;  // 0..3
  (void)ctrl;

  if (bid < ABLK) {
    // =================== A-sinkhorn u/v role (E in registers) ===============
    // Thread layout: e[j][k] = E[r0 + 8w + j][k*64 + lane], j<8, k<16.
    float* v_s = smem;          // [1024]
    float* red = smem + 1024;   // [4][1028] cross-wave col reduce
    const int b = bid;
    const int r0 = b * 32;

    // ---- prologue: e = exp(L/T) (regs only; E0 written for fp32 fallback)
    float e[8][16];
#pragma unroll
    for (int j = 0; j < 8; ++j) {
      const int r = r0 + 8 * w + j;
      const float* Lr = L + (size_t)r * N_DIM + lane;
#pragma unroll
      for (int k = 0; k < 16; ++k) e[j][k] = __expf(Lr[k * 64] * INV_T);
      if (!write_bf16) {
        float* ER = E0 + (size_t)r * N_DIM + lane;
#pragma unroll
        for (int k = 0; k < 16; ++k) ER[k * 64] = e[j][k];
      }
    }
    // v == 1 for iter 0
    v_s[t] = 1.0f;
    v_s[t + 256] = 1.0f;
    v_s[t + 512] = 1.0f;
    v_s[t + 768] = 1.0f;
    __syncthreads();

    float uF[8];
    for (int it = 0; it < 20; ++it) {
      // ---- row pass: u_i = 1/sum_c e[i][c]*v[c]
      float vv[16];
#pragma unroll
      for (int k = 0; k < 16; ++k) vv[k] = v_s[k * 64 + lane];
      float u[8];
#pragma unroll
      for (int j = 0; j < 8; ++j) {
        float p = 0.f;
#pragma unroll
        for (int k = 0; k < 16; ++k) p += e[j][k] * vv[k];
        p = wave_red_sum(p);  // lane 63
        u[j] = 1.0f /
               __int_as_float(__builtin_amdgcn_readlane(__float_as_int(p), 63));
      }
      if (it == 19) {
#pragma unroll
        for (int j = 0; j < 8; ++j) uF[j] = u[j];
      }
      // ---- col partials for this wave's 8 rows (col = k*64+lane)
#pragma unroll
      for (int k = 0; k < 16; ++k) {
        float cpl = e[0][k] * u[0] + e[1][k] * u[1] + e[2][k] * u[2] +
                    e[3][k] * u[3] + e[4][k] * u[4] + e[5][k] * u[5] +
                    e[6][k] * u[6] + e[7][k] * u[7];
        red[w * 1028 + k * 64 + lane] = cpl;
      }
      __syncthreads();
      // ---- block col sums (thread t -> cols t, t+256, t+512, t+768) + post
      float* Pit = P + (size_t)it * (ABLK * N_DIM);
#pragma unroll
      for (int cc = 0; cc < 4; ++cc) {
        const int c = t + cc * 256;
        float cp =
            red[c] + red[1028 + c] + red[2 * 1028 + c] + red[3 * 1028 + c];
        __hip_atomic_store(&Pit[b * N_DIM + c], cp, __ATOMIC_RELAXED,
                           __HIP_MEMORY_SCOPE_AGENT);
      }
      // ---- gather: parallel loads, retry only zeros (partials are > 0)
      for (int cc = 0; cc < 4; ++cc) {
        const int c = t + cc * 256;
        unsigned vals[ABLK];
#pragma unroll
        for (int pb = 0; pb < ABLK; ++pb)
          vals[pb] =
              __hip_atomic_load((const unsigned*)&Pit[pb * N_DIM + c],
                                __ATOMIC_RELAXED, __HIP_MEMORY_SCOPE_AGENT);
        for (;;) {
          unsigned miss = 0u;
#pragma unroll
          for (int pb = 0; pb < ABLK; ++pb) miss |= (vals[pb] == 0u) ? 1u : 0u;
          if (miss == 0u) break;
#pragma unroll
          for (int pb = 0; pb < ABLK; ++pb)
            if (vals[pb] == 0u)
              vals[pb] = __hip_atomic_load(
                  (const unsigned*)&Pit[pb * N_DIM + c], __ATOMIC_RELAXED,
                  __HIP_MEMORY_SCOPE_AGENT);
        }
        float s2 = 0.f;
#pragma unroll
        for (int pb = 0; pb < ABLK; ++pb) s2 += __uint_as_float(vals[pb]);
        v_s[c] = 1.0f / s2;
      }
      __syncthreads();
    }
    // ---- epilogue: write u,v (fallback path) and Mh/Ml = hi/lo(u*E*v)
    if (lane == 0) {
#pragma unroll
      for (int j = 0; j < 8; ++j) u_g[r0 + 8 * w + j] = uF[j];
    }
    if (b == 0) {
#pragma unroll
      for (int cc = 0; cc < 4; ++cc) v_g[t + cc * 256] = v_s[t + cc * 256];
    }
    if (write_bf16) {
#pragma unroll
      for (int j = 0; j < 8; ++j) {
        const int r = r0 + 8 * w + j;
        __hip_bfloat16* MhR = Mh + (size_t)r * N_DIM + lane;
        __hip_bfloat16* MlR = Ml + (size_t)r * N_DIM + lane;
#pragma unroll
        for (int k = 0; k < 16; ++k) {
          float m = e[j][k] * uF[j] * v_s[k * 64 + lane];
          __hip_bfloat16 h = __float2bfloat16(m);
          MhR[k * 64] = h;
          MlR[k * 64] = __float2bfloat16(m - __bfloat162float(h));
        }
      }
    }
    return;
  }

  // =========== W-path: one n per wave, fully in-register ====================
  float* ug = smem + w * 64;  // per-wave 256B u-broadcast line
  const int n = (bid - ABLK) * 4 + w;  // 0..1023 exactly

  const int pidx = lane << 2;  // bpermute byte index base

  // ---- logits: lane c holds E[:,c]; e[i] = exp(INV_T * sum_k w1 WV[k][i][c])
  float w1[8];
#pragma unroll
  for (int k = 0; k < 8; ++k) w1[k] = W1[n * 8 + k];
  float e[64];
#pragma unroll
  for (int i = 0; i < 64; ++i) {
    float acc = 0.f;
#pragma unroll
    for (int k = 0; k < 8; ++k) acc += w1[k] * WV[k * 4096 + i * 64 + lane];
    e[i] = __expf(acc * INV_T);
  }

  // ---- 20 sinkhorn iterations, in-wave
  float v = 1.0f;
  for (int it = 0; it < 20; ++it) {
    // row sums via register butterfly reduce-transpose:
    // lane l ends with rowsum[l] = sum_c e_c[l]*v_c
    float a[32];
    {
      const bool hi = (lane & 32) != 0;
      const int pj = pidx ^ (32 << 2);
#pragma unroll
      for (int j = 0; j < 32; ++j) {
        float s0 = (hi ? e[j] : e[j + 32]) * v;
        float k0 = (hi ? e[j + 32] : e[j]) * v;
        a[j] = k0 + __int_as_float(__builtin_amdgcn_ds_bpermute(
                        pj, __float_as_int(s0)));
      }
    }
#define BSTAGE(D)                                                          \
  {                                                                        \
    const bool hi = (lane & (D)) != 0;                                     \
    const int pj = pidx ^ ((D) << 2);                                      \
    _Pragma("unroll") for (int j = 0; j < (D); ++j) {                      \
      float s0 = hi ? a[j] : a[j + (D)];                                   \
      float k0 = hi ? a[j + (D)] : a[j];                                   \
      a[j] = k0 + __int_as_float(                                          \
                      __builtin_amdgcn_ds_bpermute(pj, __float_as_int(s0))); \
    }                                                                      \
  }
    BSTAGE(16)
    BSTAGE(8)
    BSTAGE(4)
    BSTAGE(2)
    BSTAGE(1)
#undef BSTAGE
    const float u_l = 1.0f / a[0];
    ug[lane] = u_l;  // same-wave in-order DS pipe: reads below see this
    // col pass: v_c = 1/sum_i e[i][c]*u[i]  (u broadcast, v lane-local)
    float s2 = 0.f;
#pragma unroll
    for (int q = 0; q < 16; ++q) {
      float4 u4 = *(const float4*)&ug[4 * q];
      s2 += e[4 * q] * u4.x + e[4 * q + 1] * u4.y + e[4 * q + 2] * u4.z +
            e[4 * q + 3] * u4.w;
    }
    v = 1.0f / s2;
  }

  // ---- fold u into e:  e[i] <- e[i]*u[i]   (W[i][c] = e[i]*u[i]*v)
#pragma unroll
  for (int q = 0; q < 16; ++q) {
    float4 u4 = *(const float4*)&ug[4 * q];
    e[4 * q] *= u4.x;
    e[4 * q + 1] *= u4.y;
    e[4 * q + 2] *= u4.z;
    e[4 * q + 3] *= u4.w;
  }

  // ---- in-wave matmul: x_local[bb][c] = v * sum_i x[bb][n*64+i]*e[i]
  const float* xn = x + (size_t)n * 64;
  float* xl = XL + (size_t)n * 4096;
#pragma unroll 4
  for (int bb = 0; bb < 64; ++bb) {
    const float* xr = xn + (size_t)bb * 65536;
    float acc = 0.f;
#pragma unroll
    for (int q = 0; q < 16; ++q) {
      float4 xb = *(const float4*)&xr[4 * q];  // lane-uniform -> broadcast
      acc += xb.x * e[4 * q] + xb.y * e[4 * q + 1] + xb.z * e[4 * q + 2] +
             xb.w * e[4 * q + 3];
    }
    xl[bb * 64 + lane] = acc * v;  // coalesced 256B store
  }
}

// ---------------- kernel 2b: transpose + hi/lo split -------------------------
// XTh/XTl[c][n] = hi/lo bf16 of XL[n][c].  (u,v now folded into Mh/Ml.)
__global__ __launch_bounds__(256) void k_xt(const float* __restrict__ XL,
                                            __hip_bfloat16* __restrict__ XTh,
                                            __hip_bfloat16* __restrict__ XTl) {
  __shared__ float T[64 * 68];
  const int t = threadIdx.x;
  const int n0 = blockIdx.x * 64;
  const int c0 = blockIdx.y * 64;
  {
    const int r = t >> 4;         // 0..15
    const int c4 = (t & 15) * 4;  // 0..60
#pragma unroll
    for (int p = 0; p < 4; ++p) {
      float4 f =
          *(const float4*)&XL[(size_t)(n0 + r + 16 * p) * 4096 + c0 + c4];
      *(float4*)&T[(r + 16 * p) * 68 + c4] = f;
    }
  }
  __syncthreads();
  const int cl = t >> 2;        // 0..63
  const int nb = (t & 3) * 16;  // 0,16,32,48
  __align__(16) __hip_bfloat16 hbuf[16];
  __align__(16) __hip_bfloat16 lbuf[16];
#pragma unroll
  for (int j = 0; j < 16; ++j) {
    float xv = T[(nb + j) * 68 + cl];
    __hip_bfloat16 h = __float2bfloat16(xv);
    hbuf[j] = h;
    lbuf[j] = __float2bfloat16(xv - __bfloat162float(h));
  }
  const size_t off = (size_t)(c0 + cl) * 1024 + n0 + nb;
  *(uint4*)&XTh[off] = *(uint4*)&hbuf[0];
  *(uint4*)&XTh[off + 8] = *(uint4*)&hbuf[8];
  *(uint4*)&XTl[off] = *(uint4*)&lbuf[0];
  *(uint4*)&XTl[off + 8] = *(uint4*)&lbuf[8];
}

// ---------------- kernel 3 (bf16): out = Mh*XTh + Ml*XTh + Mh*XTl ------------
// D[m=1024][c=4096], 128x128 tile, 4 waves (2x2), 16x16x32 MFMA, 4x4 frags.
// Double-buffered LDS + global_load_lds w16 + prefetch-before-MFMA:
// one barrier per K-step; load latency hides under MFMA at 1 block/CU.
__global__ __launch_bounds__(256, 2) void k_gemm3(
    const ushort* __restrict__ Mh, const ushort* __restrict__ Ml,
    const ushort* __restrict__ XTh, const ushort* __restrict__ XTl,
    float* __restrict__ out) {
  __shared__ __align__(16) ushort As[2][128 * 64];  // 2 x 16 KB
  __shared__ __align__(16) ushort Xs[2][128 * 64];  // 2 x 16 KB
  const int t = threadIdx.x;
  const int m0 = blockIdx.x * 128;
  const int c0 = blockIdx.y * 128;
  const int wid = t >> 6, lane = t & 63;
  const int wm = (wid & 1) * 64, wc = (wid >> 1) * 64;
  const int lm = lane & 15, q = lane >> 4;
  // staging: call r covers rows r*32 + wid*8 + (lane>>3), cols (lane&7)*8
  const int g_row = wid * 8 + (lane >> 3);  // + r*32
  const int g_col = (lane & 7) * 8;
  const int l_off = wid * 512;  // + r*2048 (ushort units); lane*16B added by HW

  float4v acc[4][4];
#pragma unroll
  for (int i = 0; i < 4; ++i)
#pragma unroll
    for (int j = 0; j < 4; ++j) acc[i][j] = (float4v){0.f, 0.f, 0.f, 0.f};

#define STAGE(BUF, SS)                                                       \
  {                                                                          \
    const int seg_ = (SS) >> 4;                                              \
    const int k0_ = ((SS) & 15) * 64;                                        \
    const ushort* Ag_ = (seg_ == 1) ? Ml : Mh;                               \
    const ushort* Xg_ = (seg_ == 2) ? XTl : XTh;                             \
    _Pragma("unroll") for (int r = 0; r < 4; ++r) {                          \
      stage16(Ag_ + (size_t)(m0 + r * 32 + g_row) * 1024 + k0_ + g_col,      \
              &As[BUF][r * 2048 + l_off]);                                   \
      stage16(Xg_ + (size_t)(c0 + r * 32 + g_row) * 1024 + k0_ + g_col,      \
              &Xs[BUF][r * 2048 + l_off]);                                   \
    }                                                                        \
  }

  STAGE(0, 0);
  __syncthreads();  // vmcnt(0) drain: buf0 ready
  for (int s = 0; s < 48; ++s) {
    const int cur = s & 1;
    if (s + 1 < 48) STAGE(cur ^ 1, s + 1);  // prefetch; hides under MFMA
#pragma unroll
    for (int kk = 0; kk < 2; ++kk) {
      short8 af[4], xf[4];
#pragma unroll
      for (int i = 0; i < 4; ++i)
        af[i] =
            *(const short8*)&As[cur][(wm + 16 * i + lm) * 64 + kk * 32 + q * 8];
#pragma unroll
      for (int j = 0; j < 4; ++j)
        xf[j] =
            *(const short8*)&Xs[cur][(wc + 16 * j + lm) * 64 + kk * 32 + q * 8];
#pragma unroll
      for (int i = 0; i < 4; ++i)
#pragma unroll
        for (int j = 0; j < 4; ++j)
          acc[i][j] = __builtin_amdgcn_mfma_f32_16x16x32_bf16(
              af[i], xf[j], acc[i][j], 0, 0, 0);
    }
    __syncthreads();  // prefetch complete + all reads of cur done
  }
#undef STAGE

  // epilogue: D row = q*4 + reg, col = lm (m89-verified); u,v pre-folded
#pragma unroll
  for (int i = 0; i < 4; ++i) {
#pragma unroll
    for (int j = 0; j < 4; ++j) {
      const int m = m0 + wm + 16 * i + q * 4;
      const int c = c0 + wc + 16 * j + lm;
      const int bb = c >> 6, o = c & 63;
      float* dst = out + (size_t)bb * 65536 + (size_t)m * 64 + o;
#pragma unroll
      for (int r = 0; r < 4; ++r) dst[64 * r] = acc[i][j][r];
    }
  }
}

// ---------------- kernel 3 (fp32 fallback): out = u ⊙ (E0·(v⊙XL)) ------------
__global__ __launch_bounds__(256) void k_gemm(const float* __restrict__ E0,
                                              const float* __restrict__ XL,
                                              const float* __restrict__ u_g,
                                              const float* __restrict__ v_g,
                                              float* __restrict__ out) {
  __shared__ float Asm[32][132];
  __shared__ float Xsm[32][132];
  const int t = threadIdx.x;
  const int m0 = blockIdx.x * 128;
  const int c0 = blockIdx.y * 128;
  const int my8 = (t >> 4) * 8;
  const int cx8 = (t & 15) * 8;
  const int kk = t & 31;
  const int rr = t >> 5;
  float acc[8][8] = {};

  for (int k0 = 0; k0 < 1024; k0 += 32) {
#pragma unroll
    for (int s = 0; s < 16; ++s)
      Asm[kk][rr + 8 * s] = E0[(size_t)(m0 + rr + 8 * s) * 1024 + k0 + kk];
#pragma unroll
    for (int s = 0; s < 4; ++s) {
      const int krow = k0 + rr + 8 * s;
      float vk = v_g[krow];
      float4 f = *(const float4*)&XL[(size_t)krow * 4096 + c0 + kk * 4];
      f.x *= vk;
      f.y *= vk;
      f.z *= vk;
      f.w *= vk;
      *(float4*)&Xsm[rr + 8 * s][kk * 4] = f;
    }
    __syncthreads();
#pragma unroll
    for (int k = 0; k < 32; ++k) {
      float a[8], xv[8];
      *(float4*)&a[0] = *(const float4*)&Asm[k][my8];
      *(float4*)&a[4] = *(const float4*)&Asm[k][my8 + 4];
      *(float4*)&xv[0] = *(const float4*)&Xsm[k][cx8];
      *(float4*)&xv[4] = *(const float4*)&Xsm[k][cx8 + 4];
#pragma unroll
      for (int i = 0; i < 8; ++i)
#pragma unroll
        for (int j = 0; j < 8; ++j) acc[i][j] += a[i] * xv[j];
    }
    __syncthreads();
  }

#pragma unroll
  for (int i = 0; i < 8; ++i) {
    const int m = m0 + my8 + i;
    const float um = u_g[m];
    const int c = c0 + cx8;
    const int bb = c >> 6, o = c & 63;
    float* dst = out + (size_t)bb * 65536 + (size_t)m * 64 + o;
#pragma unroll
    for (int j = 0; j < 8; ++j) dst[j] = acc[i][j] * um;
  }
}

// ---------------- launcher ---------------------------------------------------
extern "C" void kernel_launch(void* const* d_in, const int* in_sizes, int n_in,
                              void* d_out, int out_size, void* d_ws,
                              size_t ws_size, hipStream_t stream) {
  (void)in_sizes;
  (void)n_in;
  (void)out_size;
  const float* x = (const float*)d_in[0];
  const float* Alog = (const float*)d_in[1];
  const float* W1 = (const float*)d_in[2];
  const float* WV = (const float*)d_in[3];
  float* out = (float*)d_out;

  char* ws = (char*)d_ws;
  const size_t MB = 1024 * 1024;
  const size_t KB = 1024;
  const bool use_bf16 = ws_size >= (40 * MB + 256 * KB);
  const size_t P_BYTES = 20ull * ABLK * N_DIM * sizeof(float);  // 2.5 MB

  float* E0;
  float* XL;
  float* P;
  float* u_g;
  float* v_g;
  unsigned* ctrl;
  __hip_bfloat16 *Mh = nullptr, *Ml = nullptr, *XTh = nullptr, *XTl = nullptr;
  if (use_bf16) {
    P = (float*)(ws);                       // 2.5 MB (in dead E0 slot, 4 MB)
    E0 = (float*)(ws);                      // unused when write_bf16=1
    XL = (float*)(ws + 4 * MB);             // 16 MB
    Mh = (__hip_bfloat16*)(ws + 20 * MB);   // 2 MB
    Ml = (__hip_bfloat16*)(ws + 22 * MB);   // 2 MB
    XTh = (__hip_bfloat16*)(ws + 24 * MB);  // 8 MB
    XTl = (__hip_bfloat16*)(ws + 32 * MB);  // 8 MB -> 40 MB
    u_g = (float*)(ws + 40 * MB);                 // 4 KB
    v_g = (float*)(ws + 40 * MB + 4 * KB);        // 4 KB
    ctrl = (unsigned*)(ws + 40 * MB + 8 * KB);    // 4 KB (unused)
  } else {
    E0 = (float*)(ws);                      // 4 MB
    XL = (float*)(ws + 4 * MB);             // 16 MB
    P = (float*)(ws + 20 * MB);             // 2.5 MB
    u_g = (float*)(ws + 20 * MB + 2560 * KB);
    v_g = (float*)(ws + 20 * MB + 2564 * KB);
    ctrl = (unsigned*)(ws + 20 * MB + 2568 * KB);
  }

  hipMemsetAsync(P, 0, P_BYTES, stream);
  hipLaunchKernelGGL(k_front, dim3(ABLK + 256), dim3(256), 0, stream, x, Alog,
                     W1, WV, E0, Mh, Ml, P, ctrl, u_g, v_g, XL,
                     use_bf16 ? 1 : 0);
  if (use_bf16) {
    hipLaunchKernelGGL(k_xt, dim3(16, 64), dim3(256), 0, stream, XL, XTh, XTl);
    hipLaunchKernelGGL(k_gemm3, dim3(8, 32), dim3(256), 0, stream,
                       (const ushort*)Mh, (const ushort*)Ml, (const ushort*)XTh,
                       (const ushort*)XTl, out);
  } else {
    hipLaunchKernelGGL(k_gemm, dim3(8, 32), dim3(256), 0, stream, E0, XL, u_g,
                       v_g, out);
  }
}

// Round 10
// 296.906 us; speedup vs baseline: 1.0904x; 1.0694x over previous
//
#include <hip/hip_runtime.h>
#include <hip/hip_bf16.h>

// KroneckerMixer: B=64, N=1024, K=64, BASIS=8, T=0.2, 20 sinkhorn iters.
// R16 pipeline (bf16 path, ws >= 40.25 MB):
//   k_front : fused, grid 288 x 256, __launch_bounds__(256, 2) (R13 geometry,
//     no spill: VGPR=128). Blocks 0..31 = A-sinkhorn (R13-exact exchange),
//     epilogue writes Mh/Ml = hi/lo bf16 of (u*E*v) (R15 fold).
//     Blocks 32..287 = W-path (R11/R13 verified, byte-identical).
//   k_xt    : pure transpose + hi/lo split XL -> XTh/XTl bf16 [c][n].
//   k_gemm3 : R15 structure (double-buffered LDS, global_load_lds w16,
//     prefetch-before-MFMA, 1 barrier/K-step) + *** R16 fix: XOR bank
//     swizzle, both-sides (rule 21): linear LDS dest (gload_lds requires),
//     global SOURCE col-slot ^= (lane>>3)&7, ds_read slot = (kk*4+q)^(lm&7).
//     R15's unpadded [128][64] tile had 16-way ds_read conflicts (lanes
//     0..15 same col-slot, rows 128B apart -> same bank) which serialized
//     the MFMA feed (~4000 cyc/K-step vs 512 conflict-free) and nullified
//     the double-buffer gain. ***
// Fallback (small ws): fp32 k_gemm reading E0 with u/v folded.

#define N_DIM 1024
#define INV_T 5.0f
#define ABLK 32  // A-sinkhorn blocks (32 rows each)

typedef __attribute__((ext_vector_type(8))) short short8;
typedef __attribute__((ext_vector_type(4))) float float4v;

// ---------------- wave64 sum reduction via DPP (VALU pipe) -------------------
// Result valid in lane 63.
__device__ __forceinline__ float wave_red_sum(float x) {
#define DPP_ADD(C)                                                            \
  {                                                                           \
    int _y = __builtin_amdgcn_update_dpp(0, __float_as_int(x), (C), 0xf, 0xf, \
                                         true);                               \
    x += __int_as_float(_y);                                                  \
  }
  DPP_ADD(0x111);
  DPP_ADD(0x112);
  DPP_ADD(0x114);
  DPP_ADD(0x118);
  DPP_ADD(0x142);
  DPP_ADD(0x143);
#undef DPP_ADD
  return x;
}

// ---------------- async global->LDS, 16B per lane ----------------------------
// LDS dest is wave-uniform base + lane*16 (HW); global src is per-lane.
__device__ __forceinline__ void stage16(const ushort* g, ushort* l) {
  __builtin_amdgcn_global_load_lds(
      (const __attribute__((address_space(1))) void*)g,
      (__attribute__((address_space(3))) void*)l, 16, 0, 0);
}

// ---------------- kernel 1: fused sinkA(u,v)+M-emit + wpath ------------------
// grid 288 x 256.
__global__ __launch_bounds__(256, 2) void k_front(
    const float* __restrict__ x, const float* __restrict__ L,
    const float* __restrict__ W1, const float* __restrict__ WV,
    float* __restrict__ E0, __hip_bfloat16* __restrict__ Mh,
    __hip_bfloat16* __restrict__ Ml, float* __restrict__ P,
    unsigned* __restrict__ ctrl, float* __restrict__ u_g,
    float* __restrict__ v_g, float* __restrict__ XL, int write_bf16) {
  __shared__ __align__(16) float smem[5136];
  const int t = threadIdx.x;  // 0..255
  const int bid = blockIdx.x;
  const int lane = t & 63;
  const int w = t >> 6;  // 0..3
  (void)ctrl;

  if (bid < ABLK) {
    // =================== A-sinkhorn u/v role (E in registers) ===============
    // Thread layout: e[j][k] = E[r0 + 8w + j][k*64 + lane], j<8, k<16.
    float* v_s = smem;          // [1024]
    float* red = smem + 1024;   // [4][1028] cross-wave col reduce
    const int b = bid;
    const int r0 = b * 32;

    // ---- prologue: e = exp(L/T) (regs only; E0 written for fp32 fallback)
    float e[8][16];
#pragma unroll
    for (int j = 0; j < 8; ++j) {
      const int r = r0 + 8 * w + j;
      const float* Lr = L + (size_t)r * N_DIM + lane;
#pragma unroll
      for (int k = 0; k < 16; ++k) e[j][k] = __expf(Lr[k * 64] * INV_T);
      if (!write_bf16) {
        float* ER = E0 + (size_t)r * N_DIM + lane;
#pragma unroll
        for (int k = 0; k < 16; ++k) ER[k * 64] = e[j][k];
      }
    }
    // v == 1 for iter 0
    v_s[t] = 1.0f;
    v_s[t + 256] = 1.0f;
    v_s[t + 512] = 1.0f;
    v_s[t + 768] = 1.0f;
    __syncthreads();

    float uF[8];
    for (int it = 0; it < 20; ++it) {
      // ---- row pass: u_i = 1/sum_c e[i][c]*v[c]
      float vv[16];
#pragma unroll
      for (int k = 0; k < 16; ++k) vv[k] = v_s[k * 64 + lane];
      float u[8];
#pragma unroll
      for (int j = 0; j < 8; ++j) {
        float p = 0.f;
#pragma unroll
        for (int k = 0; k < 16; ++k) p += e[j][k] * vv[k];
        p = wave_red_sum(p);  // lane 63
        u[j] = 1.0f /
               __int_as_float(__builtin_amdgcn_readlane(__float_as_int(p), 63));
      }
      if (it == 19) {
#pragma unroll
        for (int j = 0; j < 8; ++j) uF[j] = u[j];
      }
      // ---- col partials for this wave's 8 rows (col = k*64+lane)
#pragma unroll
      for (int k = 0; k < 16; ++k) {
        float cpl = e[0][k] * u[0] + e[1][k] * u[1] + e[2][k] * u[2] +
                    e[3][k] * u[3] + e[4][k] * u[4] + e[5][k] * u[5] +
                    e[6][k] * u[6] + e[7][k] * u[7];
        red[w * 1028 + k * 64 + lane] = cpl;
      }
      __syncthreads();
      // ---- block col sums (thread t -> cols t, t+256, t+512, t+768) + post
      float* Pit = P + (size_t)it * (ABLK * N_DIM);
#pragma unroll
      for (int cc = 0; cc < 4; ++cc) {
        const int c = t + cc * 256;
        float cp =
            red[c] + red[1028 + c] + red[2 * 1028 + c] + red[3 * 1028 + c];
        __hip_atomic_store(&Pit[b * N_DIM + c], cp, __ATOMIC_RELAXED,
                           __HIP_MEMORY_SCOPE_AGENT);
      }
      // ---- gather: parallel loads, retry only zeros (partials are > 0)
      for (int cc = 0; cc < 4; ++cc) {
        const int c = t + cc * 256;
        unsigned vals[ABLK];
#pragma unroll
        for (int pb = 0; pb < ABLK; ++pb)
          vals[pb] =
              __hip_atomic_load((const unsigned*)&Pit[pb * N_DIM + c],
                                __ATOMIC_RELAXED, __HIP_MEMORY_SCOPE_AGENT);
        for (;;) {
          unsigned miss = 0u;
#pragma unroll
          for (int pb = 0; pb < ABLK; ++pb) miss |= (vals[pb] == 0u) ? 1u : 0u;
          if (miss == 0u) break;
#pragma unroll
          for (int pb = 0; pb < ABLK; ++pb)
            if (vals[pb] == 0u)
              vals[pb] = __hip_atomic_load(
                  (const unsigned*)&Pit[pb * N_DIM + c], __ATOMIC_RELAXED,
                  __HIP_MEMORY_SCOPE_AGENT);
        }
        float s2 = 0.f;
#pragma unroll
        for (int pb = 0; pb < ABLK; ++pb) s2 += __uint_as_float(vals[pb]);
        v_s[c] = 1.0f / s2;
      }
      __syncthreads();
    }
    // ---- epilogue: write u,v (fallback path) and Mh/Ml = hi/lo(u*E*v)
    if (lane == 0) {
#pragma unroll
      for (int j = 0; j < 8; ++j) u_g[r0 + 8 * w + j] = uF[j];
    }
    if (b == 0) {
#pragma unroll
      for (int cc = 0; cc < 4; ++cc) v_g[t + cc * 256] = v_s[t + cc * 256];
    }
    if (write_bf16) {
#pragma unroll
      for (int j = 0; j < 8; ++j) {
        const int r = r0 + 8 * w + j;
        __hip_bfloat16* MhR = Mh + (size_t)r * N_DIM + lane;
        __hip_bfloat16* MlR = Ml + (size_t)r * N_DIM + lane;
#pragma unroll
        for (int k = 0; k < 16; ++k) {
          float m = e[j][k] * uF[j] * v_s[k * 64 + lane];
          __hip_bfloat16 h = __float2bfloat16(m);
          MhR[k * 64] = h;
          MlR[k * 64] = __float2bfloat16(m - __bfloat162float(h));
        }
      }
    }
    return;
  }

  // =========== W-path: one n per wave, fully in-register ====================
  float* ug = smem + w * 64;  // per-wave 256B u-broadcast line
  const int n = (bid - ABLK) * 4 + w;  // 0..1023 exactly

  const int pidx = lane << 2;  // bpermute byte index base

  // ---- logits: lane c holds E[:,c]; e[i] = exp(INV_T * sum_k w1 WV[k][i][c])
  float w1[8];
#pragma unroll
  for (int k = 0; k < 8; ++k) w1[k] = W1[n * 8 + k];
  float e[64];
#pragma unroll
  for (int i = 0; i < 64; ++i) {
    float acc = 0.f;
#pragma unroll
    for (int k = 0; k < 8; ++k) acc += w1[k] * WV[k * 4096 + i * 64 + lane];
    e[i] = __expf(acc * INV_T);
  }

  // ---- 20 sinkhorn iterations, in-wave
  float v = 1.0f;
  for (int it = 0; it < 20; ++it) {
    // row sums via register butterfly reduce-transpose:
    // lane l ends with rowsum[l] = sum_c e_c[l]*v_c
    float a[32];
    {
      const bool hi = (lane & 32) != 0;
      const int pj = pidx ^ (32 << 2);
#pragma unroll
      for (int j = 0; j < 32; ++j) {
        float s0 = (hi ? e[j] : e[j + 32]) * v;
        float k0 = (hi ? e[j + 32] : e[j]) * v;
        a[j] = k0 + __int_as_float(__builtin_amdgcn_ds_bpermute(
                        pj, __float_as_int(s0)));
      }
    }
#define BSTAGE(D)                                                          \
  {                                                                        \
    const bool hi = (lane & (D)) != 0;                                     \
    const int pj = pidx ^ ((D) << 2);                                      \
    _Pragma("unroll") for (int j = 0; j < (D); ++j) {                      \
      float s0 = hi ? a[j] : a[j + (D)];                                   \
      float k0 = hi ? a[j + (D)] : a[j];                                   \
      a[j] = k0 + __int_as_float(                                          \
                      __builtin_amdgcn_ds_bpermute(pj, __float_as_int(s0))); \
    }                                                                      \
  }
    BSTAGE(16)
    BSTAGE(8)
    BSTAGE(4)
    BSTAGE(2)
    BSTAGE(1)
#undef BSTAGE
    const float u_l = 1.0f / a[0];
    ug[lane] = u_l;  // same-wave in-order DS pipe: reads below see this
    // col pass: v_c = 1/sum_i e[i][c]*u[i]  (u broadcast, v lane-local)
    float s2 = 0.f;
#pragma unroll
    for (int q = 0; q < 16; ++q) {
      float4 u4 = *(const float4*)&ug[4 * q];
      s2 += e[4 * q] * u4.x + e[4 * q + 1] * u4.y + e[4 * q + 2] * u4.z +
            e[4 * q + 3] * u4.w;
    }
    v = 1.0f / s2;
  }

  // ---- fold u into e:  e[i] <- e[i]*u[i]   (W[i][c] = e[i]*u[i]*v)
#pragma unroll
  for (int q = 0; q < 16; ++q) {
    float4 u4 = *(const float4*)&ug[4 * q];
    e[4 * q] *= u4.x;
    e[4 * q + 1] *= u4.y;
    e[4 * q + 2] *= u4.z;
    e[4 * q + 3] *= u4.w;
  }

  // ---- in-wave matmul: x_local[bb][c] = v * sum_i x[bb][n*64+i]*e[i]
  const float* xn = x + (size_t)n * 64;
  float* xl = XL + (size_t)n * 4096;
#pragma unroll 4
  for (int bb = 0; bb < 64; ++bb) {
    const float* xr = xn + (size_t)bb * 65536;
    float acc = 0.f;
#pragma unroll
    for (int q = 0; q < 16; ++q) {
      float4 xb = *(const float4*)&xr[4 * q];  // lane-uniform -> broadcast
      acc += xb.x * e[4 * q] + xb.y * e[4 * q + 1] + xb.z * e[4 * q + 2] +
             xb.w * e[4 * q + 3];
    }
    xl[bb * 64 + lane] = acc * v;  // coalesced 256B store
  }
}

// ---------------- kernel 2b: transpose + hi/lo split -------------------------
// XTh/XTl[c][n] = hi/lo bf16 of XL[n][c].  (u,v folded into Mh/Ml.)
__global__ __launch_bounds__(256) void k_xt(const float* __restrict__ XL,
                                            __hip_bfloat16* __restrict__ XTh,
                                            __hip_bfloat16* __restrict__ XTl) {
  __shared__ float T[64 * 68];
  const int t = threadIdx.x;
  const int n0 = blockIdx.x * 64;
  const int c0 = blockIdx.y * 64;
  {
    const int r = t >> 4;         // 0..15
    const int c4 = (t & 15) * 4;  // 0..60
#pragma unroll
    for (int p = 0; p < 4; ++p) {
      float4 f =
          *(const float4*)&XL[(size_t)(n0 + r + 16 * p) * 4096 + c0 + c4];
      *(float4*)&T[(r + 16 * p) * 68 + c4] = f;
    }
  }
  __syncthreads();
  const int cl = t >> 2;        // 0..63
  const int nb = (t & 3) * 16;  // 0,16,32,48
  __align__(16) __hip_bfloat16 hbuf[16];
  __align__(16) __hip_bfloat16 lbuf[16];
#pragma unroll
  for (int j = 0; j < 16; ++j) {
    float xv = T[(nb + j) * 68 + cl];
    __hip_bfloat16 h = __float2bfloat16(xv);
    hbuf[j] = h;
    lbuf[j] = __float2bfloat16(xv - __bfloat162float(h));
  }
  const size_t off = (size_t)(c0 + cl) * 1024 + n0 + nb;
  *(uint4*)&XTh[off] = *(uint4*)&hbuf[0];
  *(uint4*)&XTh[off + 8] = *(uint4*)&hbuf[8];
  *(uint4*)&XTl[off] = *(uint4*)&lbuf[0];
  *(uint4*)&XTl[off + 8] = *(uint4*)&lbuf[8];
}

// ---------------- kernel 3 (bf16): out = Mh*XTh + Ml*XTh + Mh*XTl ------------
// D[m=1024][c=4096], 128x128 tile, 4 waves (2x2), 16x16x32 MFMA, 4x4 frags.
// Double-buffered LDS + global_load_lds w16 + prefetch-before-MFMA, with
// XOR bank swizzle applied on BOTH sides (pre-swizzled global src + swizzled
// ds_read slot; LDS dest stays linear as gload_lds requires).
__global__ __launch_bounds__(256, 2) void k_gemm3(
    const ushort* __restrict__ Mh, const ushort* __restrict__ Ml,
    const ushort* __restrict__ XTh, const ushort* __restrict__ XTl,
    float* __restrict__ out) {
  __shared__ __align__(16) ushort As[2][128 * 64];  // 2 x 16 KB
  __shared__ __align__(16) ushort Xs[2][128 * 64];  // 2 x 16 KB
  const int t = threadIdx.x;
  const int m0 = blockIdx.x * 128;
  const int c0 = blockIdx.y * 128;
  const int wid = t >> 6, lane = t & 63;
  const int wm = (wid & 1) * 64, wc = (wid >> 1) * 64;
  const int lm = lane & 15, q = lane >> 4;
  // staging: call r covers rows r*32 + wid*8 + (lane>>3); the col 16B-slot is
  // XOR-swizzled by the row's low 3 bits ((lane>>3)&7) so that the linear LDS
  // write lands data bank-conflict-free for the swizzled ds_read below.
  const int g_row = wid * 8 + (lane >> 3);                 // + r*32
  const int g_col = ((lane & 7) ^ ((lane >> 3) & 7)) * 8;  // swizzled source
  const int l_off = wid * 512;  // + r*2048 (ushort); lane*16B added by HW

  float4v acc[4][4];
#pragma unroll
  for (int i = 0; i < 4; ++i)
#pragma unroll
    for (int j = 0; j < 4; ++j) acc[i][j] = (float4v){0.f, 0.f, 0.f, 0.f};

#define STAGE(BUF, SS)                                                       \
  {                                                                          \
    const int seg_ = (SS) >> 4;                                              \
    const int k0_ = ((SS) & 15) * 64;                                        \
    const ushort* Ag_ = (seg_ == 1) ? Ml : Mh;                               \
    const ushort* Xg_ = (seg_ == 2) ? XTl : XTh;                             \
    _Pragma("unroll") for (int r = 0; r < 4; ++r) {                          \
      stage16(Ag_ + (size_t)(m0 + r * 32 + g_row) * 1024 + k0_ + g_col,      \
              &As[BUF][r * 2048 + l_off]);                                   \
      stage16(Xg_ + (size_t)(c0 + r * 32 + g_row) * 1024 + k0_ + g_col,      \
              &Xs[BUF][r * 2048 + l_off]);                                   \
    }                                                                        \
  }

  STAGE(0, 0);
  __syncthreads();  // vmcnt(0) drain: buf0 ready
  for (int s = 0; s < 48; ++s) {
    const int cur = s & 1;
    if (s + 1 < 48) STAGE(cur ^ 1, s + 1);  // prefetch; hides under MFMA
#pragma unroll
    for (int kk = 0; kk < 2; ++kk) {
      // swizzled read slot: want 16B-slot (kk*4+q) of row; stored at
      // slot ^ (row&7), row&7 == lm&7.
      const int sa = (((kk * 4 + q) ^ (lm & 7)) * 8);
      short8 af[4], xf[4];
#pragma unroll
      for (int i = 0; i < 4; ++i)
        af[i] = *(const short8*)&As[cur][(wm + 16 * i + lm) * 64 + sa];
#pragma unroll
      for (int j = 0; j < 4; ++j)
        xf[j] = *(const short8*)&Xs[cur][(wc + 16 * j + lm) * 64 + sa];
#pragma unroll
      for (int i = 0; i < 4; ++i)
#pragma unroll
        for (int j = 0; j < 4; ++j)
          acc[i][j] = __builtin_amdgcn_mfma_f32_16x16x32_bf16(
              af[i], xf[j], acc[i][j], 0, 0, 0);
    }
    __syncthreads();  // prefetch complete + all reads of cur done
  }
#undef STAGE

  // epilogue: D row = q*4 + reg, col = lm (m89-verified); u,v pre-folded
#pragma unroll
  for (int i = 0; i < 4; ++i) {
#pragma unroll
    for (int j = 0; j < 4; ++j) {
      const int m = m0 + wm + 16 * i + q * 4;
      const int c = c0 + wc + 16 * j + lm;
      const int bb = c >> 6, o = c & 63;
      float* dst = out + (size_t)bb * 65536 + (size_t)m * 64 + o;
#pragma unroll
      for (int r = 0; r < 4; ++r) dst[64 * r] = acc[i][j][r];
    }
  }
}

// ---------------- kernel 3 (fp32 fallback): out = u ⊙ (E0·(v⊙XL)) ------------
__global__ __launch_bounds__(256) void k_gemm(const float* __restrict__ E0,
                                              const float* __restrict__ XL,
                                              const float* __restrict__ u_g,
                                              const float* __restrict__ v_g,
                                              float* __restrict__ out) {
  __shared__ float Asm[32][132];
  __shared__ float Xsm[32][132];
  const int t = threadIdx.x;
  const int m0 = blockIdx.x * 128;
  const int c0 = blockIdx.y * 128;
  const int my8 = (t >> 4) * 8;
  const int cx8 = (t & 15) * 8;
  const int kk = t & 31;
  const int rr = t >> 5;
  float acc[8][8] = {};

  for (int k0 = 0; k0 < 1024; k0 += 32) {
#pragma unroll
    for (int s = 0; s < 16; ++s)
      Asm[kk][rr + 8 * s] = E0[(size_t)(m0 + rr + 8 * s) * 1024 + k0 + kk];
#pragma unroll
    for (int s = 0; s < 4; ++s) {
      const int krow = k0 + rr + 8 * s;
      float vk = v_g[krow];
      float4 f = *(const float4*)&XL[(size_t)krow * 4096 + c0 + kk * 4];
      f.x *= vk;
      f.y *= vk;
      f.z *= vk;
      f.w *= vk;
      *(float4*)&Xsm[rr + 8 * s][kk * 4] = f;
    }
    __syncthreads();
#pragma unroll
    for (int k = 0; k < 32; ++k) {
      float a[8], xv[8];
      *(float4*)&a[0] = *(const float4*)&Asm[k][my8];
      *(float4*)&a[4] = *(const float4*)&Asm[k][my8 + 4];
      *(float4*)&xv[0] = *(const float4*)&Xsm[k][cx8];
      *(float4*)&xv[4] = *(const float4*)&Xsm[k][cx8 + 4];
#pragma unroll
      for (int i = 0; i < 8; ++i)
#pragma unroll
        for (int j = 0; j < 8; ++j) acc[i][j] += a[i] * xv[j];
    }
    __syncthreads();
  }

#pragma unroll
  for (int i = 0; i < 8; ++i) {
    const int m = m0 + my8 + i;
    const float um = u_g[m];
    const int c = c0 + cx8;
    const int bb = c >> 6, o = c & 63;
    float* dst = out + (size_t)bb * 65536 + (size_t)m * 64 + o;
#pragma unroll
    for (int j = 0; j < 8; ++j) dst[j] = acc[i][j] * um;
  }
}

// ---------------- launcher ---------------------------------------------------
extern "C" void kernel_launch(void* const* d_in, const int* in_sizes, int n_in,
                              void* d_out, int out_size, void* d_ws,
                              size_t ws_size, hipStream_t stream) {
  (void)in_sizes;
  (void)n_in;
  (void)out_size;
  const float* x = (const float*)d_in[0];
  const float* Alog = (const float*)d_in[1];
  const float* W1 = (const float*)d_in[2];
  const float* WV = (const float*)d_in[3];
  float* out = (float*)d_out;

  char* ws = (char*)d_ws;
  const size_t MB = 1024 * 1024;
  const size_t KB = 1024;
  const bool use_bf16 = ws_size >= (40 * MB + 256 * KB);
  const size_t P_BYTES = 20ull * ABLK * N_DIM * sizeof(float);  // 2.5 MB

  float* E0;
  float* XL;
  float* P;
  float* u_g;
  float* v_g;
  unsigned* ctrl;
  __hip_bfloat16 *Mh = nullptr, *Ml = nullptr, *XTh = nullptr, *XTl = nullptr;
  if (use_bf16) {
    P = (float*)(ws);                       // 2.5 MB (in dead E0 slot, 4 MB)
    E0 = (float*)(ws);                      // unused when write_bf16=1
    XL = (float*)(ws + 4 * MB);             // 16 MB
    Mh = (__hip_bfloat16*)(ws + 20 * MB);   // 2 MB
    Ml = (__hip_bfloat16*)(ws + 22 * MB);   // 2 MB
    XTh = (__hip_bfloat16*)(ws + 24 * MB);  // 8 MB
    XTl = (__hip_bfloat16*)(ws + 32 * MB);  // 8 MB -> 40 MB
    u_g = (float*)(ws + 40 * MB);                 // 4 KB
    v_g = (float*)(ws + 40 * MB + 4 * KB);        // 4 KB
    ctrl = (unsigned*)(ws + 40 * MB + 8 * KB);    // 4 KB (unused)
  } else {
    E0 = (float*)(ws);                      // 4 MB
    XL = (float*)(ws + 4 * MB);             // 16 MB
    P = (float*)(ws + 20 * MB);             // 2.5 MB
    u_g = (float*)(ws + 20 * MB + 2560 * KB);
    v_g = (float*)(ws + 20 * MB + 2564 * KB);
    ctrl = (unsigned*)(ws + 20 * MB + 2568 * KB);
  }

  hipMemsetAsync(P, 0, P_BYTES, stream);
  hipLaunchKernelGGL(k_front, dim3(ABLK + 256), dim3(256), 0, stream, x, Alog,
                     W1, WV, E0, Mh, Ml, P, ctrl, u_g, v_g, XL,
                     use_bf16 ? 1 : 0);
  if (use_bf16) {
    hipLaunchKernelGGL(k_xt, dim3(16, 64), dim3(256), 0, stream, XL, XTh, XTl);
    hipLaunchKernelGGL(k_gemm3, dim3(8, 32), dim3(256), 0, stream,
                       (const ushort*)Mh, (const ushort*)Ml, (const ushort*)XTh,
                       (const ushort*)XTl, out);
  } else {
    hipLaunchKernelGGL(k_gemm, dim3(8, 32), dim3(256), 0, stream, E0, XL, u_g,
                       v_g, out);
  }
}